// Round 1
// baseline (4380.397 us; speedup 1.0000x reference)
//
#include <hip/hip_runtime.h>

#define N_NODES 100000
#define N_EDGES 1600000

// ---------------------------------------------------------------------------
// K1: scatter-sum layer 1.  32 lanes per edge, float4 per lane (128 channels).
// agg[dst] += x[src]; deg[dst] += 1.
// ---------------------------------------------------------------------------
__global__ __launch_bounds__(256) void k_scatter1(
    const int* __restrict__ ei, const float* __restrict__ x,
    float* __restrict__ agg, float* __restrict__ deg)
{
    int tid  = threadIdx.x;
    int e    = blockIdx.x * 8 + (tid >> 5);
    if (e >= N_EDGES) return;
    int lane = tid & 31;
    int src  = ei[e];
    int dst  = ei[N_EDGES + e];
    float4 v = ((const float4*)x)[src * 32 + lane];
    float* a = agg + dst * 128 + lane * 4;
    unsafeAtomicAdd(a + 0, v.x);
    unsafeAtomicAdd(a + 1, v.y);
    unsafeAtomicAdd(a + 2, v.z);
    unsafeAtomicAdd(a + 3, v.w);
    if (lane == 0) unsafeAtomicAdd(deg + dst, 1.0f);
}

// ---------------------------------------------------------------------------
// K2: h = relu(bn( (agg/deg) @ W1l^T + b1l + x @ W1r^T ))
// Treated as C[M=100000, N=128] = A[M, K=256] * B[N, K=256]^T with
// A = [agg*invdeg | x], B = [W1l | W1r].  BM=64, BN=128, BK=32, 4x8 microtile.
// ---------------------------------------------------------------------------
__global__ __launch_bounds__(256) void k_gemm1(
    const float* __restrict__ agg, const float* __restrict__ deg,
    const float* __restrict__ x,
    const float* __restrict__ W1l, const float* __restrict__ b1l,
    const float* __restrict__ W1r,
    const float* __restrict__ gamma, const float* __restrict__ beta,
    const float* __restrict__ mean, const float* __restrict__ var,
    float* __restrict__ h)
{
    __shared__ float As[64][36];    // +4 pad: bank-spread for As[r][kk] reads
    __shared__ float Bs[32][132];   // +4 pad keeps float4 alignment
    int tid = threadIdx.x;
    int n0  = blockIdx.x * 64;
    int tx  = tid & 15, ty = tid >> 4;
    int lrow = tid >> 3;            // 0..31
    int lkq  = (tid & 7) * 4;       // 0,4,...,28
    float acc[4][8];
    #pragma unroll
    for (int i = 0; i < 4; ++i)
        #pragma unroll
        for (int j = 0; j < 8; ++j) acc[i][j] = 0.f;

    for (int kt = 0; kt < 256; kt += 32) {
        // stage A tile (64 rows x 32 k), applying invdeg on the agg half
        #pragma unroll
        for (int p = 0; p < 2; ++p) {
            int r = lrow + p * 32;
            int n = n0 + r;
            int k = kt + lkq;
            float4 v = make_float4(0.f, 0.f, 0.f, 0.f);
            if (n < N_NODES) {
                if (k < 128) {
                    v = *(const float4*)(agg + n * 128 + k);
                    float inv = 1.0f / fmaxf(deg[n], 1.0f);
                    v.x *= inv; v.y *= inv; v.z *= inv; v.w *= inv;
                } else {
                    v = *(const float4*)(x + n * 128 + (k - 128));
                }
            }
            *(float4*)&As[r][lkq] = v;
        }
        // stage B tile transposed: Bs[k][j] = W[j][k]
        #pragma unroll
        for (int p = 0; p < 4; ++p) {
            int j = lrow + p * 32;
            int k = kt + lkq;
            const float* W = (k < 128) ? (W1l + j * 128 + k)
                                       : (W1r + j * 128 + (k - 128));
            float4 v = *(const float4*)W;
            Bs[lkq + 0][j] = v.x;
            Bs[lkq + 1][j] = v.y;
            Bs[lkq + 2][j] = v.z;
            Bs[lkq + 3][j] = v.w;
        }
        __syncthreads();
        #pragma unroll
        for (int kk = 0; kk < 32; ++kk) {
            float a[4];
            #pragma unroll
            for (int i = 0; i < 4; ++i) a[i] = As[ty * 4 + i][kk];
            float4 b0 = *(const float4*)&Bs[kk][tx * 8];
            float4 b1 = *(const float4*)&Bs[kk][tx * 8 + 4];
            #pragma unroll
            for (int i = 0; i < 4; ++i) {
                acc[i][0] += a[i] * b0.x; acc[i][1] += a[i] * b0.y;
                acc[i][2] += a[i] * b0.z; acc[i][3] += a[i] * b0.w;
                acc[i][4] += a[i] * b1.x; acc[i][5] += a[i] * b1.y;
                acc[i][6] += a[i] * b1.z; acc[i][7] += a[i] * b1.w;
            }
        }
        __syncthreads();
    }
    // epilogue: bias + batchnorm + relu, float4 stores
    float sj[8], tj[8];
    #pragma unroll
    for (int jj = 0; jj < 8; ++jj) {
        int j = tx * 8 + jj;
        float s = gamma[j] * rsqrtf(var[j] + 1e-5f);
        sj[jj] = s;
        tj[jj] = beta[j] + (b1l[j] - mean[j]) * s;
    }
    #pragma unroll
    for (int i = 0; i < 4; ++i) {
        int n = n0 + ty * 4 + i;
        if (n < N_NODES) {
            float o[8];
            #pragma unroll
            for (int jj = 0; jj < 8; ++jj)
                o[jj] = fmaxf(acc[i][jj] * sj[jj] + tj[jj], 0.f);
            *(float4*)(h + n * 128 + tx * 8)     = make_float4(o[0], o[1], o[2], o[3]);
            *(float4*)(h + n * 128 + tx * 8 + 4) = make_float4(o[4], o[5], o[6], o[7]);
        }
    }
}

// ---------------------------------------------------------------------------
// K3: p2 = h @ W2l^T  (to ws, pre-aggregation via linearity)
//     out = h @ W2r^T + b2l  (to d_out; K4 adds the aggregated term)
// One GEMM: B rows 0..63 = W2l, rows 64..127 = W2r.  K=128.
// ---------------------------------------------------------------------------
__global__ __launch_bounds__(256) void k_gemm2(
    const float* __restrict__ h,
    const float* __restrict__ W2l, const float* __restrict__ b2l,
    const float* __restrict__ W2r,
    float* __restrict__ p2, float* __restrict__ out)
{
    __shared__ float As[64][36];
    __shared__ float Bs[32][132];
    int tid = threadIdx.x;
    int n0  = blockIdx.x * 64;
    int tx  = tid & 15, ty = tid >> 4;
    int lrow = tid >> 3;
    int lkq  = (tid & 7) * 4;
    float acc[4][8];
    #pragma unroll
    for (int i = 0; i < 4; ++i)
        #pragma unroll
        for (int j = 0; j < 8; ++j) acc[i][j] = 0.f;

    for (int kt = 0; kt < 128; kt += 32) {
        #pragma unroll
        for (int p = 0; p < 2; ++p) {
            int r = lrow + p * 32;
            int n = n0 + r;
            float4 v = make_float4(0.f, 0.f, 0.f, 0.f);
            if (n < N_NODES) v = *(const float4*)(h + n * 128 + kt + lkq);
            *(float4*)&As[r][lkq] = v;
        }
        #pragma unroll
        for (int p = 0; p < 4; ++p) {
            int j = lrow + p * 32;
            int k = kt + lkq;
            const float* W = (j < 64) ? (W2l + j * 128 + k)
                                      : (W2r + (j - 64) * 128 + k);
            float4 v = *(const float4*)W;
            Bs[lkq + 0][j] = v.x;
            Bs[lkq + 1][j] = v.y;
            Bs[lkq + 2][j] = v.z;
            Bs[lkq + 3][j] = v.w;
        }
        __syncthreads();
        #pragma unroll
        for (int kk = 0; kk < 32; ++kk) {
            float a[4];
            #pragma unroll
            for (int i = 0; i < 4; ++i) a[i] = As[ty * 4 + i][kk];
            float4 b0 = *(const float4*)&Bs[kk][tx * 8];
            float4 b1 = *(const float4*)&Bs[kk][tx * 8 + 4];
            #pragma unroll
            for (int i = 0; i < 4; ++i) {
                acc[i][0] += a[i] * b0.x; acc[i][1] += a[i] * b0.y;
                acc[i][2] += a[i] * b0.z; acc[i][3] += a[i] * b0.w;
                acc[i][4] += a[i] * b1.x; acc[i][5] += a[i] * b1.y;
                acc[i][6] += a[i] * b1.z; acc[i][7] += a[i] * b1.w;
            }
        }
        __syncthreads();
    }
    // epilogue: tx<8 -> p2 (cols 0..63, no bias); tx>=8 -> out (cols 0..63, +b2l)
    if (tx < 8) {
        #pragma unroll
        for (int i = 0; i < 4; ++i) {
            int n = n0 + ty * 4 + i;
            if (n < N_NODES) {
                *(float4*)(p2 + n * 64 + tx * 8)     = make_float4(acc[i][0], acc[i][1], acc[i][2], acc[i][3]);
                *(float4*)(p2 + n * 64 + tx * 8 + 4) = make_float4(acc[i][4], acc[i][5], acc[i][6], acc[i][7]);
            }
        }
    } else {
        int jb = (tx - 8) * 8;
        float bb[8];
        #pragma unroll
        for (int jj = 0; jj < 8; ++jj) bb[jj] = b2l[jb + jj];
        #pragma unroll
        for (int i = 0; i < 4; ++i) {
            int n = n0 + ty * 4 + i;
            if (n < N_NODES) {
                *(float4*)(out + n * 64 + jb)     = make_float4(acc[i][0] + bb[0], acc[i][1] + bb[1], acc[i][2] + bb[2], acc[i][3] + bb[3]);
                *(float4*)(out + n * 64 + jb + 4) = make_float4(acc[i][4] + bb[4], acc[i][5] + bb[5], acc[i][6] + bb[6], acc[i][7] + bb[7]);
            }
        }
    }
}

// ---------------------------------------------------------------------------
// K4: out[dst] += p2[src] / max(deg[dst],1).  16 lanes per edge (64 channels).
// ---------------------------------------------------------------------------
__global__ __launch_bounds__(256) void k_scatter2(
    const int* __restrict__ ei, const float* __restrict__ p2,
    const float* __restrict__ deg, float* __restrict__ out)
{
    int tid  = threadIdx.x;
    int e    = blockIdx.x * 16 + (tid >> 4);
    if (e >= N_EDGES) return;
    int lane = tid & 15;
    int src  = ei[e];
    int dst  = ei[N_EDGES + e];
    float4 v  = ((const float4*)p2)[src * 16 + lane];
    float inv = 1.0f / fmaxf(deg[dst], 1.0f);
    float* o  = out + dst * 64 + lane * 4;
    unsafeAtomicAdd(o + 0, v.x * inv);
    unsafeAtomicAdd(o + 1, v.y * inv);
    unsafeAtomicAdd(o + 2, v.z * inv);
    unsafeAtomicAdd(o + 3, v.w * inv);
}

// ---------------------------------------------------------------------------
extern "C" void kernel_launch(void* const* d_in, const int* in_sizes, int n_in,
                              void* d_out, int out_size, void* d_ws, size_t ws_size,
                              hipStream_t stream)
{
    const float* x     = (const float*)d_in[0];
    const int*   ei    = (const int*)d_in[1];
    const float* W1l   = (const float*)d_in[2];
    const float* b1l   = (const float*)d_in[3];
    const float* W1r   = (const float*)d_in[4];
    const float* gamma = (const float*)d_in[5];
    const float* beta  = (const float*)d_in[6];
    const float* mean  = (const float*)d_in[7];
    const float* var   = (const float*)d_in[8];
    const float* W2l   = (const float*)d_in[9];
    const float* b2l   = (const float*)d_in[10];
    const float* W2r   = (const float*)d_in[11];
    float* out = (float*)d_out;

    char* ws = (char*)d_ws;
    float* agg1 = (float*)ws;                        // 51.2 MB (reused as p2)
    float* h    = (float*)(ws + 51200000);           // 51.2 MB
    float* deg  = (float*)(ws + 102400000);          // 0.4 MB
    float* p2   = agg1;                              // agg1 dead after k_gemm1

    hipMemsetAsync(agg1, 0, (size_t)N_NODES * 128 * 4, stream);
    hipMemsetAsync(deg, 0, (size_t)N_NODES * 4, stream);
    k_scatter1<<<N_EDGES / 8, 256, 0, stream>>>(ei, x, agg1, deg);
    k_gemm1<<<(N_NODES + 63) / 64, 256, 0, stream>>>(agg1, deg, x, W1l, b1l, W1r,
                                                     gamma, beta, mean, var, h);
    k_gemm2<<<(N_NODES + 63) / 64, 256, 0, stream>>>(h, W2l, b2l, W2r, p2, out);
    k_scatter2<<<N_EDGES / 16, 256, 0, stream>>>(ei, p2, deg, out);
}

// Round 2
// 628.846 us; speedup vs baseline: 6.9658x; 6.9658x over previous
//
#include <hip/hip_runtime.h>

#define N_NODES 100000
#define N_EDGES 1600000
#define SCAN_BLOCKS 196   // 196*512 = 100352 >= N_NODES

// ---------------------------------------------------------------------------
// CSR build: histogram -> exclusive scan -> fill
// ---------------------------------------------------------------------------
__global__ __launch_bounds__(256) void k_hist(
    const int* __restrict__ ei, int* __restrict__ counts)
{
    int e = blockIdx.x * 256 + threadIdx.x;
    if (e < N_EDGES) atomicAdd(&counts[ei[N_EDGES + e]], 1);
}

// block-local exclusive scan of counts -> row_ptr, block totals -> blockSums
__global__ __launch_bounds__(512) void k_scan1(
    const int* __restrict__ counts, int* __restrict__ row_ptr,
    int* __restrict__ blockSums)
{
    __shared__ int s[512];
    int t = threadIdx.x;
    int i = blockIdx.x * 512 + t;
    int c = (i < N_NODES) ? counts[i] : 0;
    s[t] = c;
    __syncthreads();
    #pragma unroll
    for (int off = 1; off < 512; off <<= 1) {
        int v = (t >= off) ? s[t - off] : 0;
        __syncthreads();
        s[t] += v;
        __syncthreads();
    }
    if (i < N_NODES) row_ptr[i] = s[t] - c;   // exclusive within block
    if (t == 511) blockSums[blockIdx.x] = s[511];
}

// exclusive scan of blockSums (SCAN_BLOCKS elements) in one block
__global__ __launch_bounds__(256) void k_scan2(int* __restrict__ blockSums)
{
    __shared__ int s[256];
    int t = threadIdx.x;
    int c = (t < SCAN_BLOCKS) ? blockSums[t] : 0;
    s[t] = c;
    __syncthreads();
    #pragma unroll
    for (int off = 1; off < 256; off <<= 1) {
        int v = (t >= off) ? s[t - off] : 0;
        __syncthreads();
        s[t] += v;
        __syncthreads();
    }
    if (t < SCAN_BLOCKS) blockSums[t] = s[t] - c;
}

// add block offsets; copy to cursor; set row_ptr[N]
__global__ __launch_bounds__(512) void k_scan3(
    int* __restrict__ row_ptr, const int* __restrict__ blockSums,
    int* __restrict__ cursor)
{
    int i = blockIdx.x * 512 + threadIdx.x;
    if (i < N_NODES) {
        int v = row_ptr[i] + blockSums[blockIdx.x];
        row_ptr[i] = v;
        cursor[i]  = v;
    }
    if (i == 0) row_ptr[N_NODES] = N_EDGES;
}

__global__ __launch_bounds__(256) void k_fill(
    const int* __restrict__ ei, int* __restrict__ cursor,
    int* __restrict__ csr_src)
{
    int e = blockIdx.x * 256 + threadIdx.x;
    if (e < N_EDGES) {
        int dst = ei[N_EDGES + e];
        int pos = atomicAdd(&cursor[dst], 1);
        csr_src[pos] = ei[e];
    }
}

// ---------------------------------------------------------------------------
// K-agg1: agg[n] = sum_{e in row n} x[csr_src[e]]   (sum; /deg applied in gemm1)
// 32 lanes per node (float4 over 128 ch), 8 nodes per 256-block.
// ---------------------------------------------------------------------------
__global__ __launch_bounds__(256) void k_agg1(
    const int* __restrict__ row_ptr, const int* __restrict__ csr_src,
    const float* __restrict__ x, float* __restrict__ agg)
{
    int tid  = threadIdx.x;
    int n    = blockIdx.x * 8 + (tid >> 5);
    int lane = tid & 31;
    int e0 = row_ptr[n], e1 = row_ptr[n + 1];
    float4 acc = make_float4(0.f, 0.f, 0.f, 0.f);
    for (int e = e0; e < e1; ++e) {
        int s = csr_src[e];
        float4 v = ((const float4*)x)[s * 32 + lane];
        acc.x += v.x; acc.y += v.y; acc.z += v.z; acc.w += v.w;
    }
    ((float4*)agg)[n * 32 + lane] = acc;
}

// ---------------------------------------------------------------------------
// K2: h = relu(bn( (agg/deg) @ W1l^T + b1l + x @ W1r^T ))
// A = [agg*invdeg | x] (K=256), B = [W1l | W1r]. BM=64, BN=128, BK=32.
// ---------------------------------------------------------------------------
__global__ __launch_bounds__(256) void k_gemm1(
    const float* __restrict__ agg, const int* __restrict__ row_ptr,
    const float* __restrict__ x,
    const float* __restrict__ W1l, const float* __restrict__ b1l,
    const float* __restrict__ W1r,
    const float* __restrict__ gamma, const float* __restrict__ beta,
    const float* __restrict__ mean, const float* __restrict__ var,
    float* __restrict__ h)
{
    __shared__ float As[64][36];
    __shared__ float Bs[32][132];
    int tid = threadIdx.x;
    int n0  = blockIdx.x * 64;
    int tx  = tid & 15, ty = tid >> 4;
    int lrow = tid >> 3;
    int lkq  = (tid & 7) * 4;
    float acc[4][8];
    #pragma unroll
    for (int i = 0; i < 4; ++i)
        #pragma unroll
        for (int j = 0; j < 8; ++j) acc[i][j] = 0.f;

    for (int kt = 0; kt < 256; kt += 32) {
        #pragma unroll
        for (int p = 0; p < 2; ++p) {
            int r = lrow + p * 32;
            int n = n0 + r;
            int k = kt + lkq;
            float4 v = make_float4(0.f, 0.f, 0.f, 0.f);
            if (n < N_NODES) {
                if (k < 128) {
                    v = *(const float4*)(agg + n * 128 + k);
                    float d = (float)(row_ptr[n + 1] - row_ptr[n]);
                    float inv = 1.0f / fmaxf(d, 1.0f);
                    v.x *= inv; v.y *= inv; v.z *= inv; v.w *= inv;
                } else {
                    v = *(const float4*)(x + n * 128 + (k - 128));
                }
            }
            *(float4*)&As[r][lkq] = v;
        }
        #pragma unroll
        for (int p = 0; p < 4; ++p) {
            int j = lrow + p * 32;
            int k = kt + lkq;
            const float* W = (k < 128) ? (W1l + j * 128 + k)
                                       : (W1r + j * 128 + (k - 128));
            float4 v = *(const float4*)W;
            Bs[lkq + 0][j] = v.x;
            Bs[lkq + 1][j] = v.y;
            Bs[lkq + 2][j] = v.z;
            Bs[lkq + 3][j] = v.w;
        }
        __syncthreads();
        #pragma unroll
        for (int kk = 0; kk < 32; ++kk) {
            float a[4];
            #pragma unroll
            for (int i = 0; i < 4; ++i) a[i] = As[ty * 4 + i][kk];
            float4 b0 = *(const float4*)&Bs[kk][tx * 8];
            float4 b1 = *(const float4*)&Bs[kk][tx * 8 + 4];
            #pragma unroll
            for (int i = 0; i < 4; ++i) {
                acc[i][0] += a[i] * b0.x; acc[i][1] += a[i] * b0.y;
                acc[i][2] += a[i] * b0.z; acc[i][3] += a[i] * b0.w;
                acc[i][4] += a[i] * b1.x; acc[i][5] += a[i] * b1.y;
                acc[i][6] += a[i] * b1.z; acc[i][7] += a[i] * b1.w;
            }
        }
        __syncthreads();
    }
    float sj[8], tj[8];
    #pragma unroll
    for (int jj = 0; jj < 8; ++jj) {
        int j = tx * 8 + jj;
        float s = gamma[j] * rsqrtf(var[j] + 1e-5f);
        sj[jj] = s;
        tj[jj] = beta[j] + (b1l[j] - mean[j]) * s;
    }
    #pragma unroll
    for (int i = 0; i < 4; ++i) {
        int n = n0 + ty * 4 + i;
        if (n < N_NODES) {
            float o[8];
            #pragma unroll
            for (int jj = 0; jj < 8; ++jj)
                o[jj] = fmaxf(acc[i][jj] * sj[jj] + tj[jj], 0.f);
            *(float4*)(h + n * 128 + tx * 8)     = make_float4(o[0], o[1], o[2], o[3]);
            *(float4*)(h + n * 128 + tx * 8 + 4) = make_float4(o[4], o[5], o[6], o[7]);
        }
    }
}

// ---------------------------------------------------------------------------
// K3: p2 = h @ W2l^T ; out = h @ W2r^T + b2l
// ---------------------------------------------------------------------------
__global__ __launch_bounds__(256) void k_gemm2(
    const float* __restrict__ h,
    const float* __restrict__ W2l, const float* __restrict__ b2l,
    const float* __restrict__ W2r,
    float* __restrict__ p2, float* __restrict__ out)
{
    __shared__ float As[64][36];
    __shared__ float Bs[32][132];
    int tid = threadIdx.x;
    int n0  = blockIdx.x * 64;
    int tx  = tid & 15, ty = tid >> 4;
    int lrow = tid >> 3;
    int lkq  = (tid & 7) * 4;
    float acc[4][8];
    #pragma unroll
    for (int i = 0; i < 4; ++i)
        #pragma unroll
        for (int j = 0; j < 8; ++j) acc[i][j] = 0.f;

    for (int kt = 0; kt < 128; kt += 32) {
        #pragma unroll
        for (int p = 0; p < 2; ++p) {
            int r = lrow + p * 32;
            int n = n0 + r;
            float4 v = make_float4(0.f, 0.f, 0.f, 0.f);
            if (n < N_NODES) v = *(const float4*)(h + n * 128 + kt + lkq);
            *(float4*)&As[r][lkq] = v;
        }
        #pragma unroll
        for (int p = 0; p < 4; ++p) {
            int j = lrow + p * 32;
            int k = kt + lkq;
            const float* W = (j < 64) ? (W2l + j * 128 + k)
                                      : (W2r + (j - 64) * 128 + k);
            float4 v = *(const float4*)W;
            Bs[lkq + 0][j] = v.x;
            Bs[lkq + 1][j] = v.y;
            Bs[lkq + 2][j] = v.z;
            Bs[lkq + 3][j] = v.w;
        }
        __syncthreads();
        #pragma unroll
        for (int kk = 0; kk < 32; ++kk) {
            float a[4];
            #pragma unroll
            for (int i = 0; i < 4; ++i) a[i] = As[ty * 4 + i][kk];
            float4 b0 = *(const float4*)&Bs[kk][tx * 8];
            float4 b1 = *(const float4*)&Bs[kk][tx * 8 + 4];
            #pragma unroll
            for (int i = 0; i < 4; ++i) {
                acc[i][0] += a[i] * b0.x; acc[i][1] += a[i] * b0.y;
                acc[i][2] += a[i] * b0.z; acc[i][3] += a[i] * b0.w;
                acc[i][4] += a[i] * b1.x; acc[i][5] += a[i] * b1.y;
                acc[i][6] += a[i] * b1.z; acc[i][7] += a[i] * b1.w;
            }
        }
        __syncthreads();
    }
    if (tx < 8) {
        #pragma unroll
        for (int i = 0; i < 4; ++i) {
            int n = n0 + ty * 4 + i;
            if (n < N_NODES) {
                *(float4*)(p2 + n * 64 + tx * 8)     = make_float4(acc[i][0], acc[i][1], acc[i][2], acc[i][3]);
                *(float4*)(p2 + n * 64 + tx * 8 + 4) = make_float4(acc[i][4], acc[i][5], acc[i][6], acc[i][7]);
            }
        }
    } else {
        int jb = (tx - 8) * 8;
        float bb[8];
        #pragma unroll
        for (int jj = 0; jj < 8; ++jj) bb[jj] = b2l[jb + jj];
        #pragma unroll
        for (int i = 0; i < 4; ++i) {
            int n = n0 + ty * 4 + i;
            if (n < N_NODES) {
                *(float4*)(out + n * 64 + jb)     = make_float4(acc[i][0] + bb[0], acc[i][1] + bb[1], acc[i][2] + bb[2], acc[i][3] + bb[3]);
                *(float4*)(out + n * 64 + jb + 4) = make_float4(acc[i][4] + bb[4], acc[i][5] + bb[5], acc[i][6] + bb[6], acc[i][7] + bb[7]);
            }
        }
    }
}

// ---------------------------------------------------------------------------
// K-agg2: out[n] += (sum_{e in row n} p2[csr_src[e]]) / max(deg,1)
// 16 lanes per node (float4 over 64 ch), 16 nodes per 256-block. Non-atomic.
// ---------------------------------------------------------------------------
__global__ __launch_bounds__(256) void k_agg2(
    const int* __restrict__ row_ptr, const int* __restrict__ csr_src,
    const float* __restrict__ p2, float* __restrict__ out)
{
    int tid  = threadIdx.x;
    int n    = blockIdx.x * 16 + (tid >> 4);
    int lane = tid & 15;
    int e0 = row_ptr[n], e1 = row_ptr[n + 1];
    float4 acc = make_float4(0.f, 0.f, 0.f, 0.f);
    for (int e = e0; e < e1; ++e) {
        int s = csr_src[e];
        float4 v = ((const float4*)p2)[s * 16 + lane];
        acc.x += v.x; acc.y += v.y; acc.z += v.z; acc.w += v.w;
    }
    float inv = 1.0f / fmaxf((float)(e1 - e0), 1.0f);
    float4* o = (float4*)out + n * 16 + lane;
    float4 cur = *o;
    cur.x += acc.x * inv; cur.y += acc.y * inv;
    cur.z += acc.z * inv; cur.w += acc.w * inv;
    *o = cur;
}

// ---------------------------------------------------------------------------
extern "C" void kernel_launch(void* const* d_in, const int* in_sizes, int n_in,
                              void* d_out, int out_size, void* d_ws, size_t ws_size,
                              hipStream_t stream)
{
    const float* x     = (const float*)d_in[0];
    const int*   ei    = (const int*)d_in[1];
    const float* W1l   = (const float*)d_in[2];
    const float* b1l   = (const float*)d_in[3];
    const float* W1r   = (const float*)d_in[4];
    const float* gamma = (const float*)d_in[5];
    const float* beta  = (const float*)d_in[6];
    const float* mean  = (const float*)d_in[7];
    const float* var   = (const float*)d_in[8];
    const float* W2l   = (const float*)d_in[9];
    const float* b2l   = (const float*)d_in[10];
    const float* W2r   = (const float*)d_in[11];
    float* out = (float*)d_out;

    char* ws = (char*)d_ws;
    float* agg1    = (float*)ws;                     // 51.2 MB (reused as p2)
    float* h       = (float*)(ws + 51200000);        // 51.2 MB
    int*   row_ptr = (int*)(ws + 102400000);         // 400 KB
    int*   csr_src = (int*)(ws + 102801408);         // 6.4 MB
    int*   blockSums = (int*)(ws + 109201408);       // 1 KB
    // counts & cursor alias the (not-yet-written) h region: dead before gemm1.
    int*   counts  = (int*)h;
    int*   cursor  = (int*)(h + 131072);
    float* p2      = agg1;

    hipMemsetAsync(counts, 0, N_NODES * sizeof(int), stream);
    k_hist<<<(N_EDGES + 255) / 256, 256, 0, stream>>>(ei, counts);
    k_scan1<<<SCAN_BLOCKS, 512, 0, stream>>>(counts, row_ptr, blockSums);
    k_scan2<<<1, 256, 0, stream>>>(blockSums);
    k_scan3<<<SCAN_BLOCKS, 512, 0, stream>>>(row_ptr, blockSums, cursor);
    k_fill<<<(N_EDGES + 255) / 256, 256, 0, stream>>>(ei, cursor, csr_src);
    k_agg1<<<N_NODES / 8, 256, 0, stream>>>(row_ptr, csr_src, x, agg1);
    k_gemm1<<<(N_NODES + 63) / 64, 256, 0, stream>>>(agg1, row_ptr, x, W1l, b1l, W1r,
                                                     gamma, beta, mean, var, h);
    k_gemm2<<<(N_NODES + 63) / 64, 256, 0, stream>>>(h, W2l, b2l, W2r, p2, out);
    k_agg2<<<N_NODES / 16, 256, 0, stream>>>(row_ptr, csr_src, p2, out);
}